// Round 16
// baseline (271.257 us; speedup 1.0000x reference)
//
#include <hip/hip_runtime.h>
#include <math.h>

#define CC 4
#define HH 64
#define WW 64
#define NN (HH*WW)
#define NTH 256
#define GRP 4            // 4 float4-groups per thread = 16 pixels/thread
#define LDW 65           // padded LDS row stride: window reads are 2-way (free)

typedef float vf4 __attribute__((ext_vector_type(4)));   // native vector for nontemporal builtins

#if __has_builtin(__builtin_amdgcn_exp2f)
#define FEXP2(x) __builtin_amdgcn_exp2f(x)
#else
#define FEXP2(x) exp2f(x)
#endif
#if __has_builtin(__builtin_amdgcn_logf)
#define FLOG2(x) __builtin_amdgcn_logf(x)   // v_log_f32 = log2
#else
#define FLOG2(x) log2f(x)
#endif
#define LOG2E 1.4426950408889634f

__device__ __forceinline__ float softplusf(float x) {
    return (x > 20.f) ? x : log1pf(expf(x));
}
__device__ __forceinline__ float sigmoidf(float x) {
    return 1.f / (1.f + expf(-x));
}

// one-barrier block reduce; each call must use a DISTINCT scratch slot sc[4]
__device__ __forceinline__ float bred(float v, float* sc, bool do_max) {
#pragma unroll
    for (int o = 32; o > 0; o >>= 1) {
        float other = __shfl_down(v, o, 64);
        v = do_max ? fmaxf(v, other) : (v + other);
    }
    if ((threadIdx.x & 63) == 0) sc[threadIdx.x >> 6] = v;
    __syncthreads();
    return do_max ? fmaxf(fmaxf(sc[0], sc[1]), fmaxf(sc[2], sc[3]))
                  : ((sc[0] + sc[1]) + (sc[2] + sc[3]));
}

// block=256: 4 waves/block; min 5 waves/EU -> 5 blocks/CU, caps VGPR at 102
// (natural allocation is 104 -> 4 blocks/CU; the 2-reg squeeze buys +25% TLP)
__global__ __launch_bounds__(NTH, 5)
void slam_kernel(const float* __restrict__ map_state,
                 const float* __restrict__ weight_state,
                 const float* __restrict__ key,
                 const float* __restrict__ beta,
                 const float* __restrict__ gate,
                 const float* __restrict__ shift,
                 const float* __restrict__ sharpen,
                 const float* __restrict__ add_patch_logits,
                 const float* __restrict__ erase_patch_logits,
                 float* __restrict__ out_map,
                 float* __restrict__ out_w,
                 float* __restrict__ out_rv)
{
    __shared__ float sw[HH * LDW];      // 16.6 KB single weight-field buffer
    __shared__ float spatch[2 * CC * 9];
    __shared__ float sks[9];            // shift kernel (broadcast reads)
    __shared__ float sred[8][4];

    const int b = blockIdx.x;
    const int tid = threadIdx.x;

    // ---- per-batch scalars (per-thread redundant; cheap) ----
    const float* keyb = key + b * CC;
    float k0 = keyb[0], k1 = keyb[1], k2 = keyb[2], k3 = keyb[3];
    {
        float inv = rsqrtf(fmaxf(k0*k0 + k1*k1 + k2*k2 + k3*k3, 1e-24f));
        k0 *= inv; k1 *= inv; k2 *= inv; k3 *= inv;
    }
    const float beta_pos  = softplusf(beta[b]) + 1e-6f;
    const float g         = sigmoidf(gate[b]);
    const float sharp_pos = 1.f + softplusf(sharpen[b]);

    // shift-kernel softmax -> LDS (tid 0 only; 9 elements)
    if (tid == 0) {
        const float* sh = shift + b * 9;
        float m = sh[0];
#pragma unroll
        for (int i = 1; i < 9; ++i) m = fmaxf(m, sh[i]);
        float s = 0.f;
        float e[9];
#pragma unroll
        for (int i = 0; i < 9; ++i) { e[i] = FEXP2((sh[i] - m) * LOG2E); s += e[i]; }
        float inv = 1.f / s;
#pragma unroll
        for (int i = 0; i < 9; ++i) sks[i] = e[i] * inv;
    }

    // patch sigmoids into LDS
    if (tid < 2 * CC * 9) {
        float v = (tid < CC * 9) ? add_patch_logits[b * CC * 9 + tid]
                                 : erase_patch_logits[b * CC * 9 + (tid - CC * 9)];
        spatch[tid] = sigmoidf(v);
    }

    const vf4* mp4 = (const vf4*)(map_state    + (size_t)b * CC * NN);
    const vf4* pw4 = (const vf4*)(weight_state + (size_t)b * NN);
    vf4*       om4 = (vf4*)(out_map + (size_t)b * CC * NN);
    vf4*       ow4 = (vf4*)(out_w   + (size_t)b * NN);

    float z[16];   // per-thread staging: logits -> exp -> sharpened

    // ---- Phase 1a: similarity logits (registers only) ----
    float lmax = -INFINITY;
#pragma unroll 1
    for (int gix = 0; gix < GRP; ++gix) {
        const int base = tid + gix * NTH;       // float4 index; pixel P = 4*base
        vf4 mv0 = mp4[base];
        vf4 mv1 = mp4[(NN/4) + base];
        vf4 mv2 = mp4[2*(NN/4) + base];
        vf4 mv3 = mp4[3*(NN/4) + base];
#pragma unroll
        for (int j = 0; j < 4; ++j) {
            float a0 = mv0[j];
            float a1 = mv1[j];
            float a2 = mv2[j];
            float a3 = mv3[j];
            float inv = rsqrtf(fmaxf(a0*a0 + a1*a1 + a2*a2 + a3*a3, 1e-24f));
            float zz = beta_pos * (a0*k0 + a1*k1 + a2*k2 + a3*k3) * inv;
            z[gix*4 + j] = zz;
            lmax = fmaxf(lmax, zz);
        }
    }
    const float zmax = bred(lmax, sred[0], true);

    float lsum = 0.f;
#pragma unroll
    for (int i = 0; i < 16; ++i) {
        float e = FEXP2((z[i] - zmax) * LOG2E);
        z[i] = e;
        lsum += e;
    }
    const float Z = bred(lsum, sred[1], false);
    const float gZinv = g / Z;
    const float g1 = 1.f - g;

    // gate-blend -> LDS  (pw is read-once: non-temporal)
#pragma unroll
    for (int gix = 0; gix < GRP; ++gix) {
        const int base = tid + gix * NTH;
        const int P = 4 * base, h = P >> 6, w0 = P & 63;
        vf4 pw = __builtin_nontemporal_load(&pw4[base]);
        float* row = sw + h * LDW + w0;
#pragma unroll
        for (int j = 0; j < 4; ++j)
            row[j] = gZinv * z[gix*4 + j] + g1 * pw[j];
    }
    __syncthreads();

    // ---- Phase 2: circular 3x3 conv + sharpen (row-wise accumulation) ----
    float lsum1 = 0.f;
#pragma unroll
    for (int gix = 0; gix < GRP; ++gix) {
        const int P = 4 * (tid + gix * NTH), h = P >> 6, w0 = P & 63;
        const int rr[3] = { (h + 1) & 63, h, (h + 63) & 63 };   // dh=0,1,2
        const int cm = (w0 + 63) & 63, cp = (w0 + 4) & 63;
        float acc0 = 0.f, acc1 = 0.f, acc2 = 0.f, acc3 = 0.f;
#pragma unroll
        for (int dh = 0; dh < 3; ++dh) {
            const float* rp = sw + rr[dh] * LDW;
            float b0 = rp[cm];
            float b1 = rp[w0];
            float b2 = rp[w0 + 1];
            float b3 = rp[w0 + 2];
            float b4 = rp[w0 + 3];
            float b5 = rp[cp];
            float s0 = sks[dh*3+0], s1 = sks[dh*3+1], s2 = sks[dh*3+2];
            acc0 += s0*b2 + s1*b1 + s2*b0;
            acc1 += s0*b3 + s1*b2 + s2*b1;
            acc2 += s0*b4 + s1*b3 + s2*b2;
            acc3 += s0*b5 + s1*b4 + s2*b3;
        }
        float p0 = FEXP2(sharp_pos * FLOG2(fmaxf(acc0, 1e-6f)));
        float p1 = FEXP2(sharp_pos * FLOG2(fmaxf(acc1, 1e-6f)));
        float p2 = FEXP2(sharp_pos * FLOG2(fmaxf(acc2, 1e-6f)));
        float p3 = FEXP2(sharp_pos * FLOG2(fmaxf(acc3, 1e-6f)));
        z[gix*4+0] = p0; z[gix*4+1] = p1; z[gix*4+2] = p2; z[gix*4+3] = p3;
        lsum1 += (p0 + p1) + (p2 + p3);
    }
    const float S1 = bred(lsum1, sred[2], false);   // barrier: all conv reads done
    const float inv1 = 1.f / (S1 + 1e-6f);
    const float S2 = S1 * inv1;                     // sum of first-normalized weights
    const float scale = inv1 / (S2 + 1e-6f);

    // final weights -> LDS + global (streaming write: non-temporal)
#pragma unroll
    for (int gix = 0; gix < GRP; ++gix) {
        const int base = tid + gix * NTH;
        const int P = 4 * base, h = P >> 6, w0 = P & 63;
        float* row = sw + h * LDW + w0;
        vf4 o;
#pragma unroll
        for (int j = 0; j < 4; ++j) {
            float wv = z[gix*4 + j] * scale;
            row[j] = wv;
            o[j] = wv;
        }
        __builtin_nontemporal_store(o, &ow4[base]);
    }
    __syncthreads();

    // ---- Phase 3: patch apply (zero-pad), map update, read vector ----
    float rv[CC] = {0.f, 0.f, 0.f, 0.f};
#pragma unroll 1
    for (int gix = 0; gix < GRP; ++gix) {
        const int base = tid + gix * NTH;
        const int P = 4 * base, h = P >> 6, w0 = P & 63;
        float buf[3][6];
#pragma unroll
        for (int dh = 0; dh < 3; ++dh) {
            const int r = h + 1 - dh;
            if ((unsigned)r < (unsigned)HH) {
                const float* rp = sw + r * LDW;
                buf[dh][0] = (w0 > 0) ? rp[w0 - 1] : 0.f;
                buf[dh][1] = rp[w0];
                buf[dh][2] = rp[w0 + 1];
                buf[dh][3] = rp[w0 + 2];
                buf[dh][4] = rp[w0 + 3];
                buf[dh][5] = (w0 + 4 < WW) ? rp[w0 + 4] : 0.f;
            } else {
#pragma unroll
                for (int k = 0; k < 6; ++k) buf[dh][k] = 0.f;
            }
        }
        const float wn0 = buf[1][1], wn1 = buf[1][2], wn2 = buf[1][3], wn3 = buf[1][4];
#pragma unroll
        for (int ch = 0; ch < CC; ++ch) {
            // second (and last) touch of map lines: non-temporal
            vf4 m4 = __builtin_nontemporal_load(&mp4[ch * (NN/4) + base]);
            float a0 = 0.f, a1 = 0.f, a2 = 0.f, a3 = 0.f;
            float e0 = 0.f, e1 = 0.f, e2 = 0.f, e3 = 0.f;
#pragma unroll
            for (int dh = 0; dh < 3; ++dh) {
#pragma unroll
                for (int t = 0; t < 3; ++t) {
                    const float ca = spatch[ch * 9 + dh * 3 + t];
                    const float ce = spatch[CC * 9 + ch * 9 + dh * 3 + t];
                    // coefficient t multiplies window value buf[dh][j+2-t]
                    a0 += ca * buf[dh][2 - t];  e0 += ce * buf[dh][2 - t];
                    a1 += ca * buf[dh][3 - t];  e1 += ce * buf[dh][3 - t];
                    a2 += ca * buf[dh][4 - t];  e2 += ce * buf[dh][4 - t];
                    a3 += ca * buf[dh][5 - t];  e3 += ce * buf[dh][5 - t];
                }
            }
            vf4 o;
            float mu;
            mu = m4[0] * (1.f - fminf(fmaxf(e0, 0.f), 1.f)) + a0;
            o[0] = mu; rv[ch] += mu * wn0;
            mu = m4[1] * (1.f - fminf(fmaxf(e1, 0.f), 1.f)) + a1;
            o[1] = mu; rv[ch] += mu * wn1;
            mu = m4[2] * (1.f - fminf(fmaxf(e2, 0.f), 1.f)) + a2;
            o[2] = mu; rv[ch] += mu * wn2;
            mu = m4[3] * (1.f - fminf(fmaxf(e3, 0.f), 1.f)) + a3;
            o[3] = mu; rv[ch] += mu * wn3;
            __builtin_nontemporal_store(o, &om4[ch * (NN/4) + base]);
        }
    }

    // read-vector block reduction (4 channels)
#pragma unroll
    for (int c = 0; c < CC; ++c) {
        float v = rv[c];
#pragma unroll
        for (int o = 32; o > 0; o >>= 1) v += __shfl_down(v, o, 64);
        if ((tid & 63) == 0) sred[4 + c][tid >> 6] = v;
    }
    __syncthreads();
    if (tid == 0) {
#pragma unroll
        for (int c = 0; c < CC; ++c)
            out_rv[(size_t)b * CC + c] =
                (sred[4+c][0] + sred[4+c][1]) + (sred[4+c][2] + sred[4+c][3]);
    }
}

extern "C" void kernel_launch(void* const* d_in, const int* in_sizes, int n_in,
                              void* d_out, int out_size, void* d_ws, size_t ws_size,
                              hipStream_t stream) {
    const float* map_state          = (const float*)d_in[0];
    const float* weight_state       = (const float*)d_in[1];
    const float* key                = (const float*)d_in[2];
    const float* beta               = (const float*)d_in[3];
    const float* gate               = (const float*)d_in[4];
    const float* shift              = (const float*)d_in[5];
    const float* sharpen            = (const float*)d_in[6];
    // d_in[7] = erase, d_in[8] = add : unused by the reference
    const float* add_patch_logits   = (const float*)d_in[9];
    const float* erase_patch_logits = (const float*)d_in[10];

    const int B = in_sizes[1] / NN;   // weight_state is (B, H*W)

    float* out_map = (float*)d_out;
    float* out_w   = out_map + (size_t)B * CC * NN;
    float* out_rv  = out_w   + (size_t)B * NN;

    slam_kernel<<<B, NTH, 0, stream>>>(map_state, weight_state, key, beta, gate,
                                       shift, sharpen, add_patch_logits,
                                       erase_patch_logits, out_map, out_w, out_rv);
}

// Round 17
// 78.048 us; speedup vs baseline: 3.4755x; 3.4755x over previous
//
#include <hip/hip_runtime.h>
#include <math.h>

#define CC 4
#define HH 64
#define WW 64
#define NN (HH*WW)
#define NTH 256
#define GRP 4            // 4 float4-groups per thread = 16 pixels/thread
#define LDW 65           // padded LDS row stride: window reads are 2-way (free)

typedef float vf4 __attribute__((ext_vector_type(4)));   // native vector for nontemporal builtins

#if __has_builtin(__builtin_amdgcn_exp2f)
#define FEXP2(x) __builtin_amdgcn_exp2f(x)
#else
#define FEXP2(x) exp2f(x)
#endif
#if __has_builtin(__builtin_amdgcn_logf)
#define FLOG2(x) __builtin_amdgcn_logf(x)   // v_log_f32 = log2
#else
#define FLOG2(x) log2f(x)
#endif
#define LOG2E 1.4426950408889634f

__device__ __forceinline__ float softplusf(float x) {
    return (x > 20.f) ? x : log1pf(expf(x));
}
__device__ __forceinline__ float sigmoidf(float x) {
    return 1.f / (1.f + expf(-x));
}

// one-barrier block reduce; each call must use a DISTINCT scratch slot sc[4]
__device__ __forceinline__ float bred(float v, float* sc, bool do_max) {
#pragma unroll
    for (int o = 32; o > 0; o >>= 1) {
        float other = __shfl_down(v, o, 64);
        v = do_max ? fmaxf(v, other) : (v + other);
    }
    if ((threadIdx.x & 63) == 0) sc[threadIdx.x >> 6] = v;
    __syncthreads();
    return do_max ? fmaxf(fmaxf(sc[0], sc[1]), fmaxf(sc[2], sc[3]))
                  : ((sc[0] + sc[1]) + (sc[2] + sc[3]));
}

// NOTE: no min-waves arg. (256,5) collapses the allocator to 48 VGPR and
// spills ~550 MB to scratch (r16: 271 us). Natural allocation = 104 VGPR,
// 4 blocks/CU -> 78 us (r13).
__global__ __launch_bounds__(NTH)
void slam_kernel(const float* __restrict__ map_state,
                 const float* __restrict__ weight_state,
                 const float* __restrict__ key,
                 const float* __restrict__ beta,
                 const float* __restrict__ gate,
                 const float* __restrict__ shift,
                 const float* __restrict__ sharpen,
                 const float* __restrict__ add_patch_logits,
                 const float* __restrict__ erase_patch_logits,
                 float* __restrict__ out_map,
                 float* __restrict__ out_w,
                 float* __restrict__ out_rv)
{
    __shared__ float sw[HH * LDW];      // 16.6 KB single weight-field buffer
    __shared__ float spatch[2 * CC * 9];
    __shared__ float sks[9];            // shift kernel (broadcast reads)
    __shared__ float sred[8][4];

    const int b = blockIdx.x;
    const int tid = threadIdx.x;

    // ---- per-batch scalars (per-thread redundant; cheap) ----
    const float* keyb = key + b * CC;
    float k0 = keyb[0], k1 = keyb[1], k2 = keyb[2], k3 = keyb[3];
    {
        float inv = rsqrtf(fmaxf(k0*k0 + k1*k1 + k2*k2 + k3*k3, 1e-24f));
        k0 *= inv; k1 *= inv; k2 *= inv; k3 *= inv;
    }
    const float beta_pos  = softplusf(beta[b]) + 1e-6f;
    const float g         = sigmoidf(gate[b]);
    const float sharp_pos = 1.f + softplusf(sharpen[b]);

    // shift-kernel softmax -> LDS (tid 0 only; 9 elements)
    if (tid == 0) {
        const float* sh = shift + b * 9;
        float m = sh[0];
#pragma unroll
        for (int i = 1; i < 9; ++i) m = fmaxf(m, sh[i]);
        float s = 0.f;
        float e[9];
#pragma unroll
        for (int i = 0; i < 9; ++i) { e[i] = FEXP2((sh[i] - m) * LOG2E); s += e[i]; }
        float inv = 1.f / s;
#pragma unroll
        for (int i = 0; i < 9; ++i) sks[i] = e[i] * inv;
    }

    // patch sigmoids into LDS
    if (tid < 2 * CC * 9) {
        float v = (tid < CC * 9) ? add_patch_logits[b * CC * 9 + tid]
                                 : erase_patch_logits[b * CC * 9 + (tid - CC * 9)];
        spatch[tid] = sigmoidf(v);
    }

    const vf4* mp4 = (const vf4*)(map_state    + (size_t)b * CC * NN);
    const vf4* pw4 = (const vf4*)(weight_state + (size_t)b * NN);
    vf4*       om4 = (vf4*)(out_map + (size_t)b * CC * NN);
    vf4*       ow4 = (vf4*)(out_w   + (size_t)b * NN);

    float z[16];   // per-thread staging: logits -> exp -> sharpened

    // ---- Phase 1a: similarity logits (registers only) ----
    float lmax = -INFINITY;
#pragma unroll 1
    for (int gix = 0; gix < GRP; ++gix) {
        const int base = tid + gix * NTH;       // float4 index; pixel P = 4*base
        vf4 mv0 = mp4[base];
        vf4 mv1 = mp4[(NN/4) + base];
        vf4 mv2 = mp4[2*(NN/4) + base];
        vf4 mv3 = mp4[3*(NN/4) + base];
#pragma unroll
        for (int j = 0; j < 4; ++j) {
            float a0 = mv0[j];
            float a1 = mv1[j];
            float a2 = mv2[j];
            float a3 = mv3[j];
            float inv = rsqrtf(fmaxf(a0*a0 + a1*a1 + a2*a2 + a3*a3, 1e-24f));
            float zz = beta_pos * (a0*k0 + a1*k1 + a2*k2 + a3*k3) * inv;
            z[gix*4 + j] = zz;
            lmax = fmaxf(lmax, zz);
        }
    }
    const float zmax = bred(lmax, sred[0], true);

    float lsum = 0.f;
#pragma unroll
    for (int i = 0; i < 16; ++i) {
        float e = FEXP2((z[i] - zmax) * LOG2E);
        z[i] = e;
        lsum += e;
    }
    const float Z = bred(lsum, sred[1], false);
    const float gZinv = g / Z;
    const float g1 = 1.f - g;

    // gate-blend -> LDS  (pw is read-once: non-temporal)
#pragma unroll
    for (int gix = 0; gix < GRP; ++gix) {
        const int base = tid + gix * NTH;
        const int P = 4 * base, h = P >> 6, w0 = P & 63;
        vf4 pw = __builtin_nontemporal_load(&pw4[base]);
        float* row = sw + h * LDW + w0;
#pragma unroll
        for (int j = 0; j < 4; ++j)
            row[j] = gZinv * z[gix*4 + j] + g1 * pw[j];
    }
    __syncthreads();

    // ---- Phase 2: circular 3x3 conv + sharpen (row-wise accumulation) ----
    float lsum1 = 0.f;
#pragma unroll
    for (int gix = 0; gix < GRP; ++gix) {
        const int P = 4 * (tid + gix * NTH), h = P >> 6, w0 = P & 63;
        const int rr[3] = { (h + 1) & 63, h, (h + 63) & 63 };   // dh=0,1,2
        const int cm = (w0 + 63) & 63, cp = (w0 + 4) & 63;
        float acc0 = 0.f, acc1 = 0.f, acc2 = 0.f, acc3 = 0.f;
#pragma unroll
        for (int dh = 0; dh < 3; ++dh) {
            const float* rp = sw + rr[dh] * LDW;
            float b0 = rp[cm];
            float b1 = rp[w0];
            float b2 = rp[w0 + 1];
            float b3 = rp[w0 + 2];
            float b4 = rp[w0 + 3];
            float b5 = rp[cp];
            float s0 = sks[dh*3+0], s1 = sks[dh*3+1], s2 = sks[dh*3+2];
            acc0 += s0*b2 + s1*b1 + s2*b0;
            acc1 += s0*b3 + s1*b2 + s2*b1;
            acc2 += s0*b4 + s1*b3 + s2*b2;
            acc3 += s0*b5 + s1*b4 + s2*b3;
        }
        float p0 = FEXP2(sharp_pos * FLOG2(fmaxf(acc0, 1e-6f)));
        float p1 = FEXP2(sharp_pos * FLOG2(fmaxf(acc1, 1e-6f)));
        float p2 = FEXP2(sharp_pos * FLOG2(fmaxf(acc2, 1e-6f)));
        float p3 = FEXP2(sharp_pos * FLOG2(fmaxf(acc3, 1e-6f)));
        z[gix*4+0] = p0; z[gix*4+1] = p1; z[gix*4+2] = p2; z[gix*4+3] = p3;
        lsum1 += (p0 + p1) + (p2 + p3);
    }
    const float S1 = bred(lsum1, sred[2], false);   // barrier: all conv reads done
    const float inv1 = 1.f / (S1 + 1e-6f);
    const float S2 = S1 * inv1;                     // sum of first-normalized weights
    const float scale = inv1 / (S2 + 1e-6f);

    // final weights -> LDS + global (streaming write: non-temporal)
#pragma unroll
    for (int gix = 0; gix < GRP; ++gix) {
        const int base = tid + gix * NTH;
        const int P = 4 * base, h = P >> 6, w0 = P & 63;
        float* row = sw + h * LDW + w0;
        vf4 o;
#pragma unroll
        for (int j = 0; j < 4; ++j) {
            float wv = z[gix*4 + j] * scale;
            row[j] = wv;
            o[j] = wv;
        }
        __builtin_nontemporal_store(o, &ow4[base]);
    }
    __syncthreads();

    // ---- Phase 3: patch apply (zero-pad), map update, read vector ----
    float rv[CC] = {0.f, 0.f, 0.f, 0.f};
#pragma unroll 1
    for (int gix = 0; gix < GRP; ++gix) {
        const int base = tid + gix * NTH;
        const int P = 4 * base, h = P >> 6, w0 = P & 63;
        float buf[3][6];
#pragma unroll
        for (int dh = 0; dh < 3; ++dh) {
            const int r = h + 1 - dh;
            if ((unsigned)r < (unsigned)HH) {
                const float* rp = sw + r * LDW;
                buf[dh][0] = (w0 > 0) ? rp[w0 - 1] : 0.f;
                buf[dh][1] = rp[w0];
                buf[dh][2] = rp[w0 + 1];
                buf[dh][3] = rp[w0 + 2];
                buf[dh][4] = rp[w0 + 3];
                buf[dh][5] = (w0 + 4 < WW) ? rp[w0 + 4] : 0.f;
            } else {
#pragma unroll
                for (int k = 0; k < 6; ++k) buf[dh][k] = 0.f;
            }
        }
        const float wn0 = buf[1][1], wn1 = buf[1][2], wn2 = buf[1][3], wn3 = buf[1][4];
#pragma unroll
        for (int ch = 0; ch < CC; ++ch) {
            // second (and last) touch of map lines: non-temporal
            vf4 m4 = __builtin_nontemporal_load(&mp4[ch * (NN/4) + base]);
            float a0 = 0.f, a1 = 0.f, a2 = 0.f, a3 = 0.f;
            float e0 = 0.f, e1 = 0.f, e2 = 0.f, e3 = 0.f;
#pragma unroll
            for (int dh = 0; dh < 3; ++dh) {
#pragma unroll
                for (int t = 0; t < 3; ++t) {
                    const float ca = spatch[ch * 9 + dh * 3 + t];
                    const float ce = spatch[CC * 9 + ch * 9 + dh * 3 + t];
                    // coefficient t multiplies window value buf[dh][j+2-t]
                    a0 += ca * buf[dh][2 - t];  e0 += ce * buf[dh][2 - t];
                    a1 += ca * buf[dh][3 - t];  e1 += ce * buf[dh][3 - t];
                    a2 += ca * buf[dh][4 - t];  e2 += ce * buf[dh][4 - t];
                    a3 += ca * buf[dh][5 - t];  e3 += ce * buf[dh][5 - t];
                }
            }
            vf4 o;
            float mu;
            mu = m4[0] * (1.f - fminf(fmaxf(e0, 0.f), 1.f)) + a0;
            o[0] = mu; rv[ch] += mu * wn0;
            mu = m4[1] * (1.f - fminf(fmaxf(e1, 0.f), 1.f)) + a1;
            o[1] = mu; rv[ch] += mu * wn1;
            mu = m4[2] * (1.f - fminf(fmaxf(e2, 0.f), 1.f)) + a2;
            o[2] = mu; rv[ch] += mu * wn2;
            mu = m4[3] * (1.f - fminf(fmaxf(e3, 0.f), 1.f)) + a3;
            o[3] = mu; rv[ch] += mu * wn3;
            __builtin_nontemporal_store(o, &om4[ch * (NN/4) + base]);
        }
    }

    // read-vector block reduction (4 channels)
#pragma unroll
    for (int c = 0; c < CC; ++c) {
        float v = rv[c];
#pragma unroll
        for (int o = 32; o > 0; o >>= 1) v += __shfl_down(v, o, 64);
        if ((tid & 63) == 0) sred[4 + c][tid >> 6] = v;
    }
    __syncthreads();
    if (tid == 0) {
#pragma unroll
        for (int c = 0; c < CC; ++c)
            out_rv[(size_t)b * CC + c] =
                (sred[4+c][0] + sred[4+c][1]) + (sred[4+c][2] + sred[4+c][3]);
    }
}

extern "C" void kernel_launch(void* const* d_in, const int* in_sizes, int n_in,
                              void* d_out, int out_size, void* d_ws, size_t ws_size,
                              hipStream_t stream) {
    const float* map_state          = (const float*)d_in[0];
    const float* weight_state       = (const float*)d_in[1];
    const float* key                = (const float*)d_in[2];
    const float* beta               = (const float*)d_in[3];
    const float* gate               = (const float*)d_in[4];
    const float* shift              = (const float*)d_in[5];
    const float* sharpen            = (const float*)d_in[6];
    // d_in[7] = erase, d_in[8] = add : unused by the reference
    const float* add_patch_logits   = (const float*)d_in[9];
    const float* erase_patch_logits = (const float*)d_in[10];

    const int B = in_sizes[1] / NN;   // weight_state is (B, H*W)

    float* out_map = (float*)d_out;
    float* out_w   = out_map + (size_t)B * CC * NN;
    float* out_rv  = out_w   + (size_t)B * NN;

    slam_kernel<<<B, NTH, 0, stream>>>(map_state, weight_state, key, beta, gate,
                                       shift, sharpen, add_patch_logits,
                                       erase_patch_logits, out_map, out_w, out_rv);
}